// Round 5
// baseline (1495.308 us; speedup 1.0000x reference)
//
#include <hip/hip_runtime.h>
#include <hip/hip_bf16.h>

#define IN_C   128
#define HID    16
#define OUT_C  8
#define EDGE_C 16
#define NG     64
#define NRANGE 8     // dst ranges, pinned to XCDs via blockIdx % 8
#define BSHIFT 5     // 32 nodes per bucket
#define BNODES 32
#define NBUCK_MAX 4096   // cursor array sizing (N up to 131072)

// ---------------------------------------------------------------------------
__global__ void deg_kernel(const int* __restrict__ dst, int* __restrict__ deg, int E) {
    int e = blockIdx.x * blockDim.x + threadIdx.x;
    if (e < E) atomicAdd(&deg[dst[e]], 1);
}

// Exclusive scan stage A: per-256-block Hillis-Steele (writes exclusive-within-block)
__global__ void scanA_kernel(const int* __restrict__ deg, int* __restrict__ row_start,
                             int* __restrict__ blocksum, int n) {
    __shared__ int s[256];
    int t = threadIdx.x;
    int i = blockIdx.x * 256 + t;
    int own = (i < n) ? deg[i] : 0;
    s[t] = own; __syncthreads();
    for (int off = 1; off < 256; off <<= 1) {
        int v = (t >= off) ? s[t - off] : 0;
        __syncthreads();
        s[t] += v;
        __syncthreads();
    }
    if (i < n) row_start[i] = s[t] - own;
    if (t == 255) blocksum[blockIdx.x] = s[255];
}

__global__ void scanB_kernel(int* __restrict__ blocksum, int nb) {
    __shared__ int s[512];
    int t = threadIdx.x;
    int own = (t < nb) ? blocksum[t] : 0;
    s[t] = own; __syncthreads();
    for (int off = 1; off < 512; off <<= 1) {
        int v = (t >= off) ? s[t - off] : 0;
        __syncthreads();
        s[t] += v;
        __syncthreads();
    }
    if (t < nb) blocksum[t] = s[t] - own;
}

// row_start += blockoff (in place); dinv = rsqrt(deg+1)
__global__ void scanC_kernel(const int* __restrict__ deg, int* __restrict__ row_start,
                             const int* __restrict__ blocksum,
                             float* __restrict__ dinv, int n) {
    int i = blockIdx.x * 256 + threadIdx.x;
    if (i < n) {
        row_start[i] = row_start[i] + blocksum[blockIdx.x];
        dinv[i] = rsqrtf((float)deg[i] + 1.0f);
    }
}

// XCD-pinned bucket binning. Bucket = 32 consecutive dst nodes; stream lives IN
// PLACE at adj[row_start[bucket_base]...]. Cursors padded one per 64B line.
// Chain per counter = E/3125 = 1024 atomics x ~50ns ≈ 51us (round-4 measured
// 50ns/same-address atomic at chain=4096 -> 208us; this is the 4x shrink).
// Entry: .x = e, .y = src | (d_local << 25), d_local in [0,32).
__global__ void bin_kernel(const int* __restrict__ src, const int* __restrict__ dst,
                           const int* __restrict__ row_start, int* __restrict__ bcur,
                           int2* __restrict__ adj, int E, int range_size, int bpr) {
    int r = blockIdx.x & (NRANGE - 1);
    int q = blockIdx.x >> 3;
    int lo = r * range_size;
    int hi = lo + range_size;
    long long chunk = ((long long)E + bpr - 1) / bpr;
    int e0 = (int)((long long)q * chunk);
    long long e1l = (long long)e0 + chunk;
    int e1 = (e1l < E) ? (int)e1l : E;
#pragma unroll 4
    for (int e = e0 + threadIdx.x; e < e1; e += blockDim.x) {
        int d = __builtin_nontemporal_load(dst + e);
        if (d >= lo && d < hi) {
            int s = __builtin_nontemporal_load(src + e);
            int b = d >> BSHIFT;
            int base = row_start[d & ~(BNODES - 1)];      // bucket span base (L2-hot)
            int pos = base + atomicAdd(&bcur[b << 4], 1); // padded: 1 counter / line
            adj[pos] = make_int2(e, s | ((d & (BNODES - 1)) << 25));
        }
    }
}

// a1[v][c] = dinv[v] * (x[v] @ W1_node)[c]
__global__ void xform1_kernel(const float* __restrict__ x, const float* __restrict__ W,
                              const float* __restrict__ dinv, float* __restrict__ a1, int n) {
    int t = threadIdx.x;
    int v = blockIdx.x * 16 + (t >> 4);
    int c = t & 15;
    if (v >= n) return;
    const float4* xr = (const float4*)(x + (size_t)v * IN_C);
    float acc = 0.0f;
#pragma unroll
    for (int k4 = 0; k4 < IN_C / 4; ++k4) {
        float4 xv = xr[k4];
        int k = k4 * 4;
        acc += xv.x * W[(k + 0) * HID + c];
        acc += xv.y * W[(k + 1) * HID + c];
        acc += xv.z * W[(k + 2) * HID + c];
        acc += xv.w * W[(k + 3) * HID + c];
    }
    a1[(size_t)v * HID + c] = dinv[v] * acc;
}

// Layer-1 fused bucket gather: one block per 32-node bucket.
// Streams the bucket's edge span SEQUENTIALLY (16 slots x 16 channels), scatter-
// adds ds*ea and a1[src] into LDS accumulators, then does both 16x16 matvecs
// (ES@W1e, h1@W2n) in-block. No per-node CSR order needed -> csr_kernel deleted.
__global__ void gatherA_kernel(const int2* __restrict__ adj, const int* __restrict__ row_start,
                               const float* __restrict__ edge_attr,
                               const float* __restrict__ W1e, const float* __restrict__ W2n,
                               const float* __restrict__ a1, const float* __restrict__ dinv,
                               float* __restrict__ a2, float* __restrict__ ES_g,
                               int n, int E) {
    __shared__ float S1[BNODES * HID];     // sum a1[src]
    __shared__ float ESs[BNODES * HID];    // sum ds*ea
    __shared__ float Hs[BNODES * HID];     // h1 staging
    __shared__ float W1s[EDGE_C * HID];
    __shared__ float W2s[HID * HID];
    int t = threadIdx.x;
    int b = blockIdx.x;
    int lo = b << BSHIFT;
    W1s[t] = W1e[t];                        // 256 each
    W2s[t] = W2n[t];
    S1[t] = 0.0f; S1[t + 256] = 0.0f;
    ESs[t] = 0.0f; ESs[t + 256] = 0.0f;
    __syncthreads();
    int base = row_start[lo];
    int hi_node = lo + BNODES;
    int end = (hi_node < n) ? row_start[hi_node] : E;
    int slot = t >> 4;
    int c = t & 15;
#pragma unroll 4
    for (int i = base + slot; i < end; i += 16) {
        long long adv = __builtin_nontemporal_load((const long long*)&adj[i]);
        int e = (int)(adv & 0xffffffffLL);
        int y = (int)(adv >> 32);
        int s  = y & ((1 << 25) - 1);
        int dl = ((unsigned)y) >> 25;
        float ds = dinv[s];
        float ea = __builtin_nontemporal_load(edge_attr + (size_t)e * EDGE_C + c);
        float av = a1[s * HID + c];
        atomicAdd(&ESs[dl * HID + c], ds * ea);
        atomicAdd(&S1[dl * HID + c], av);
    }
    __syncthreads();
    // epilogue: 2 halves of 16 nodes x 16 channels
#pragma unroll
    for (int half = 0; half < 2; ++half) {
        int nl = half * 16 + slot;
        int v = lo + nl;
        float h = 0.0f;
        if (v < n) {
            float dv = dinv[v];
            float e1 = 0.0f;
#pragma unroll
            for (int k = 0; k < EDGE_C; ++k)
                e1 += ESs[nl * HID + k] * W1s[k * HID + c];
            h = fmaxf(dv * (S1[nl * HID + c] + a1[(size_t)v * HID + c] + e1), 0.0f);
        }
        Hs[nl * HID + c] = h;
    }
    __syncthreads();
#pragma unroll
    for (int half = 0; half < 2; ++half) {
        int nl = half * 16 + slot;
        int v = lo + nl;
        if (v < n) {
            float o = 0.0f;
#pragma unroll
            for (int k = 0; k < HID; ++k)
                o += Hs[nl * HID + k] * W2s[k * HID + c];
            a2[(size_t)v * HID + c] = dinv[v] * o;
            ES_g[(size_t)v * HID + c] = ESs[nl * HID + c];
        }
    }
}

// Layer-2 fused bucket gather: neighbor-sum of a2 + ES@W2e epilogue.
__global__ void gatherB_kernel(const int2* __restrict__ adj, const int* __restrict__ row_start,
                               const float* __restrict__ W2e,
                               const float* __restrict__ a2, const float* __restrict__ dinv,
                               const float* __restrict__ ES_g, float* __restrict__ h2,
                               int n, int E) {
    __shared__ float S2[BNODES * HID];
    __shared__ float ESs[BNODES * HID];
    __shared__ float Ws[EDGE_C * HID];
    int t = threadIdx.x;
    int b = blockIdx.x;
    int lo = b << BSHIFT;
    Ws[t] = W2e[t];
    S2[t] = 0.0f; S2[t + 256] = 0.0f;
    {   // coalesced ES stage (2 x 1KB)
        size_t nb16 = (size_t)n * HID;
        size_t i0 = (size_t)lo * HID + t;
        ESs[t]       = (i0 < nb16)       ? ES_g[i0]       : 0.0f;
        ESs[t + 256] = (i0 + 256 < nb16) ? ES_g[i0 + 256] : 0.0f;
    }
    __syncthreads();
    int base = row_start[lo];
    int hi_node = lo + BNODES;
    int end = (hi_node < n) ? row_start[hi_node] : E;
    int slot = t >> 4;
    int c = t & 15;
#pragma unroll 4
    for (int i = base + slot; i < end; i += 16) {
        long long adv = __builtin_nontemporal_load((const long long*)&adj[i]);
        int y = (int)(adv >> 32);
        int s  = y & ((1 << 25) - 1);
        int dl = ((unsigned)y) >> 25;
        float av = a2[s * HID + c];            // L3-resident (6.4 MB)
        atomicAdd(&S2[dl * HID + c], av);
    }
    __syncthreads();
#pragma unroll
    for (int half = 0; half < 2; ++half) {
        int nl = half * 16 + slot;
        int v = lo + nl;
        if (v < n) {
            float dv = dinv[v];
            float e2 = 0.0f;
#pragma unroll
            for (int k = 0; k < EDGE_C; ++k)
                e2 += ESs[nl * HID + k] * Ws[k * HID + c];
            float h = fmaxf(dv * (S2[nl * HID + c] + a2[(size_t)v * HID + c] + e2), 0.0f);
            h2[(size_t)v * HID + c] = h;
        }
    }
}

// One block per graph: binary-search sorted batch for [start,end), LDS-reduce, 16x8 head.
__global__ void pool_final_kernel(const float* __restrict__ h2,
                                  const int* __restrict__ batch,
                                  const float* __restrict__ W, const float* __restrict__ b,
                                  float* __restrict__ out, int n) {
    __shared__ float sdata[256];
    int g = blockIdx.x;
    int t = threadIdx.x;
    int c = t & 15;
    int lo = 0, hi = n;
    while (lo < hi) { int m = (lo + hi) >> 1; if (batch[m] < g) lo = m + 1; else hi = m; }
    int start = lo;
    hi = n;
    while (lo < hi) { int m = (lo + hi) >> 1; if (batch[m] < g + 1) lo = m + 1; else hi = m; }
    int end = lo;
    float acc = 0.0f;
    for (int v = start + (t >> 4); v < end; v += 16)
        acc += h2[(size_t)v * HID + c];
    sdata[t] = acc; __syncthreads();
    for (int s = 128; s >= 16; s >>= 1) {
        if (t < s) sdata[t] += sdata[t + s];
        __syncthreads();
    }
    if (t < OUT_C) {
        float inv = 1.0f / fmaxf((float)(end - start), 1.0f);
        float o = b[t];
#pragma unroll
        for (int cc = 0; cc < HID; ++cc)
            o += sdata[cc] * inv * W[cc * OUT_C + t];
        out[g * OUT_C + t] = o;
    }
}

// ---------------------------------------------------------------------------
extern "C" void kernel_launch(void* const* d_in, const int* in_sizes, int n_in,
                              void* d_out, int out_size, void* d_ws, size_t ws_size,
                              hipStream_t stream) {
    const float* x         = (const float*)d_in[0];
    const int*   edge_idx  = (const int*)d_in[1];
    const float* edge_attr = (const float*)d_in[2];
    const int*   batch     = (const int*)d_in[3];
    const float* W1_node   = (const float*)d_in[4];
    const float* W1_edge   = (const float*)d_in[5];
    const float* W2_node   = (const float*)d_in[6];
    const float* W2_edge   = (const float*)d_in[7];
    const float* node_W    = (const float*)d_in[8];
    const float* node_b    = (const float*)d_in[9];
    float* out = (float*)d_out;

    const int N = in_sizes[0] / IN_C;
    const int E = in_sizes[1] / 2;
    const int* src = edge_idx;
    const int* dst = edge_idx + E;

    // Workspace layout (adj first for 8B alignment). deg+bcur adjacent -> one memset.
    char* p = (char*)d_ws;
    int2*  adj       = (int2*)p;   p += sizeof(int2) * (size_t)E;
    int*   deg       = (int*)p;    p += sizeof(int) * (size_t)N;        // zeroed
    int*   bcur      = (int*)p;    p += sizeof(int) * NBUCK_MAX * 16;   // zeroed, 64B-strided
    int*   row_start = (int*)p;    p += sizeof(int) * (size_t)N;
    int*   blocksum  = (int*)p;    p += sizeof(int) * 512;
    float* dinv      = (float*)p;  p += sizeof(float) * (size_t)N;
    float* a1        = (float*)p;  p += sizeof(float) * (size_t)HID * N;
    float* a2        = (float*)p;  p += sizeof(float) * (size_t)HID * N;
    float* ES        = (float*)p;  p += sizeof(float) * (size_t)HID * N;
    float* h2        = a1;         // a1 dead after gatherA

    hipMemsetAsync(deg, 0, sizeof(int) * ((size_t)N + NBUCK_MAX * 16), stream);

    const int tb = 256;
    const int nbN = (N + 255) / 256;
    deg_kernel <<<(E + tb - 1) / tb, tb, 0, stream>>>(dst, deg, E);
    scanA_kernel<<<nbN, 256, 0, stream>>>(deg, row_start, blocksum, N);
    scanB_kernel<<<1, 512, 0, stream>>>(blocksum, nbN);
    scanC_kernel<<<nbN, 256, 0, stream>>>(deg, row_start, blocksum, dinv, N);

    const int range_size = (N + NRANGE - 1) / NRANGE;
    const int bpr = 256;                       // blocks per range -> 2048 blocks total
    bin_kernel<<<NRANGE * bpr, tb, 0, stream>>>(src, dst, row_start, bcur, adj, E, range_size, bpr);

    xform1_kernel<<<(N + 15) / 16, tb, 0, stream>>>(x, W1_node, dinv, a1, N);

    const int nbuck = (N + BNODES - 1) >> BSHIFT;
    gatherA_kernel<<<nbuck, 256, 0, stream>>>(
        adj, row_start, edge_attr, W1_edge, W2_node, a1, dinv, a2, ES, N, E);
    gatherB_kernel<<<nbuck, 256, 0, stream>>>(
        adj, row_start, W2_edge, a2, dinv, ES, h2, N, E);

    pool_final_kernel<<<NG, 256, 0, stream>>>(h2, batch, node_W, node_b, out, N);
}